// Round 14
// baseline (221.271 us; speedup 1.0000x reference)
//
#include <hip/hip_runtime.h>
#include <hip/hip_bf16.h>

typedef __attribute__((ext_vector_type(8))) __bf16 bf16x8;
typedef __attribute__((ext_vector_type(4))) float  f32x4;

#define SDIM 49
#define NDIM 1024
#define CDIM 384
#define DDIM 512
#define DMC  64
#define SCALE (1.0f/(SDIM*NDIM))
#define SLOT 65536   // A(keys) 32KB + B(q) 32KB per K-step slot; 2 slots = 128KB
#define CHUNK 24576  // floats copied per tile: 1568*24576 == 2*1024*384*49

__device__ __forceinline__ void gload16(const void* g, void* l) {
    __builtin_amdgcn_global_load_lds((const __attribute__((address_space(1))) void*)g,
                                     (__attribute__((address_space(3))) void*)l, 16, 0, 0);
}

// ---------------------------------------------------------------------------
// pack only (copy lives in loss kernel): x [N,C,S] + m + c -> bf16 [S,N,512].
// ---------------------------------------------------------------------------
__global__ __launch_bounds__(512) void pack_kernel(
    const float* __restrict__ xloc, const float* __restrict__ mv,
    const float* __restrict__ cv,   __hip_bfloat16* __restrict__ dst)
{
    const int j = blockIdx.x;
    const int d = threadIdx.x;
    float vals[SDIM];
    if (d < CDIM) {
        const float* p = xloc + ((size_t)j * CDIM + d) * SDIM;
        #pragma unroll
        for (int s = 0; s < SDIM; ++s) vals[s] = p[s];
    } else if (d < CDIM + DMC) {
        float v = mv[j * DMC + (d - CDIM)];
        #pragma unroll
        for (int s = 0; s < SDIM; ++s) vals[s] = v;
    } else {
        float v = cv[j * DMC + (d - CDIM - DMC)];
        #pragma unroll
        for (int s = 0; s < SDIM; ++s) vals[s] = v;
    }
    #pragma unroll
    for (int s = 0; s < SDIM; ++s)
        dst[((size_t)s * NDIM + j) * DDIM + d] = __float2bfloat16(vals[s]);
}

// fpack also zero-inits the loss accumulator (replaces the memset dispatch).
__global__ void fpack_kernel(const float* __restrict__ f,
                             __hip_bfloat16* __restrict__ dst, int n,
                             float* __restrict__ out0)
{
    int i = blockIdx.x * blockDim.x + threadIdx.x;
    if (i == 0) out0[0] = 0.0f;
    if (i < n) dst[i] = __float2bfloat16(f[i]);
}

// ---------------------------------------------------------------------------
// PERSISTENT fused GEMM + partial-LSE + hidden passthrough copy (R13) with
// WAVE-PHASE ANTI-ALIGNMENT: waves pair onto SIMDs as (w, w+4) = (wk=0,1);
// giving the two groups opposite kc order makes one group's 12 ds_reads
// overlap the other group's 32 MFMAs instead of phase-locking (R13: LDS and
// MFMA bursts summed -> 36% MfmaUtil ceiling).
// Everything else identical to R13 (validated): grid 256x512 persistent,
// tile 256x256 BK=64, minimal-sync 1-barrier K-step, stage8 pinned first,
// XOR-swizzled LDS (0 conflicts), C/D col=lane&15 row=(lane>>4)*4+reg,
// copy of CHUNK floats per tile at peak marginal HBM BW.
// ---------------------------------------------------------------------------
__global__ __launch_bounds__(512, 2) void loss_kernel(
    const __hip_bfloat16* __restrict__ Fm,   // [N,512]
    const __hip_bfloat16* __restrict__ Km,   // [S,N,512] keys
    const __hip_bfloat16* __restrict__ Qm,   // [S,N,512] queries (pred2)
    const float* __restrict__ xp,            // copy source 1
    const float* __restrict__ xq,            // copy source 2
    float* __restrict__ outv,                // out+1 (copy dest)
    float2* __restrict__ part,               // [S*2048][8]
    float* __restrict__ out)
{
    extern __shared__ __attribute__((aligned(16))) char sm[];   // 2*SLOT

    const int bid = blockIdx.x;
    const int xcd = bid & 7;
    const int jj  = bid >> 3;
    const int g0  = 196 * xcd;
    const int gend = g0 + 196;

    const int tid  = threadIdx.x;
    const int lane = tid & 63;
    const int w    = tid >> 6;
    const int l15  = lane & 15;
    const int l4   = lane >> 4;   // 0..3
    const int wk   = w >> 2;      // 0..1 key half (also SIMD-pair parity)
    const int wq   = w & 3;       // 0..3 q quarter

    const int trow = tid >> 3;
    const int scol = (((tid & 7) ^ ((tid >> 3) & 7)) << 4);

    const unsigned xo   = (unsigned)((l15 & 7) << 4);
    const unsigned arow = (unsigned)((wk * 128 + l15) * 128);
    const unsigned brow = 32768u + (unsigned)((wq * 64 + l15) * 128);

    // anti-phase kc order per SIMD-pair
    const int kcA = wk;          // first kc half this wave reads
    const int kcB = 1 - wk;

    auto APtr = [&](int g) -> const char* {
        const int s = g >> 5, kb = (g >> 3) & 3;
        return (const char*)Km + ((size_t)s * NDIM + (size_t)kb * 256) * 1024;
    };
    auto BPtr = [&](int g) -> const char* {
        const int s = g >> 5, qb = g & 7;
        return (qb < 4)
            ? ((const char*)Fm + (size_t)qb * 256 * 1024)
            : ((const char*)Qm + ((size_t)s * NDIM + (size_t)(qb - 4) * 256) * 1024);
    };
    auto stage8 = [&](const char* A, const char* B, int ko, char* slot) {
        #pragma unroll
        for (int c = 0; c < 4; ++c) {
            gload16(A + (size_t)(c * 64 + trow) * 1024 + ko + scol,
                    slot + c * 8192 + tid * 16);
            gload16(B + (size_t)(c * 64 + trow) * 1024 + ko + scol,
                    slot + 32768 + c * 8192 + tid * 16);
        }
    };

    f32x4 acc[8][4];
    bf16x8 afr[8], bfr[4];

    #define READ12(KC) do {                                                   \
        const unsigned co = ((unsigned)((KC) * 64 + l4 * 16)) ^ xo;           \
        _Pragma("unroll")                                                     \
        for (int a = 0; a < 8; ++a)                                           \
            afr[a] = *(const bf16x8*)(sb_ + arow + a * 2048u + co);           \
        _Pragma("unroll")                                                     \
        for (int b = 0; b < 4; ++b)                                           \
            bfr[b] = *(const bf16x8*)(sb_ + brow + b * 2048u + co);           \
    } while (0)

    #define MFMA32() do {                                                     \
        _Pragma("unroll")                                                     \
        for (int a = 0; a < 8; ++a)                                           \
            _Pragma("unroll")                                                 \
            for (int b = 0; b < 4; ++b)                                       \
                acc[a][b] = __builtin_amdgcn_mfma_f32_16x16x32_bf16(          \
                    afr[a], bfr[b], acc[a][b], 0, 0, 0);                      \
    } while (0)

    // prologue: first tile's step 0 into slot 0
    stage8(APtr(g0 + jj), BPtr(g0 + jj), 0, sm);

    for (int g = g0 + jj; g < gend; g += 32) {
        const char* Ag = APtr(g);
        const char* Bg = BPtr(g);
        const bool hasNext = (g + 32) < gend;
        const char* An = hasNext ? APtr(g + 32) : Ag;
        const char* Bn = hasNext ? BPtr(g + 32) : Bg;

        #pragma unroll
        for (int a = 0; a < 8; ++a)
            #pragma unroll
            for (int b = 0; b < 4; ++b) acc[a][b] = f32x4{0.f, 0.f, 0.f, 0.f};

        #pragma unroll
        for (int t = 0; t < 8; ++t) {
            const char* sb_ = sm + (size_t)(t & 1) * SLOT;
            char* ns_ = sm + (size_t)((t + 1) & 1) * SLOT;

            __syncthreads();   // vmcnt0+lgkm0 drain = slot handoff (R10)

            if ((t < 7) || hasNext) {
                const char* sA = (t < 7) ? Ag : An;
                const char* sB = (t < 7) ? Bg : Bn;
                stage8(sA, sB, (t < 7) ? (t + 1) * 128 : 0, ns_);
            }
            __builtin_amdgcn_sched_barrier(0);   // pin stage-issue first

            // anti-phase: wk=0 waves do kc0 first, wk=1 waves kc1 first ->
            // each SIMD's two resident waves overlap LDS reads with MFMAs.
            READ12(kcA);
            __builtin_amdgcn_s_setprio(1); MFMA32(); __builtin_amdgcn_s_setprio(0);
            READ12(kcB);
            __builtin_amdgcn_s_setprio(1); MFMA32(); __builtin_amdgcn_s_setprio(0);
        }

        // ---- epilogue (overlaps next tile's in-flight step-0 loads)
        const int s  = g >> 5;
        const int kb = (g >> 3) & 3;
        const int qb = g & 7;

        // copy loads issued first: latency hides under the LSE math below
        const float* csrc = (g < 784) ? (xp + (size_t)g * CHUNK)
                                      : (xq + (size_t)(g - 784) * CHUNK);
        float* cdst = outv + (size_t)g * CHUNK;
        f32x4 cbuf[12];
        #pragma unroll
        for (int i = 0; i < 12; ++i)
            cbuf[i] = *(const f32x4*)(csrc + tid * 4 + i * 2048);

        float q_m[4], q_s[4];
        #pragma unroll
        for (int b = 0; b < 4; ++b) {
            float m = -3.0e38f;
            #pragma unroll
            for (int a = 0; a < 8; ++a)
                #pragma unroll
                for (int r = 0; r < 4; ++r) m = fmaxf(m, acc[a][b][r]);
            float ss = 0.0f;
            #pragma unroll
            for (int a = 0; a < 8; ++a)
                #pragma unroll
                for (int r = 0; r < 4; ++r) ss += __expf(acc[a][b][r] - m);
            #pragma unroll
            for (int off = 16; off <= 32; off <<= 1) {
                float mo = __shfl_xor(m, off, 64);
                float so = __shfl_xor(ss, off, 64);
                float nm = fmaxf(m, mo);
                ss = ss * __expf(m - nm) + so * __expf(mo - nm);
                m = nm;
            }
            q_m[b] = m; q_s[b] = ss;
        }

        // diag (reads acc) before the copy stores
        if (kb == (qb & 3) && (wq >> 1) == wk) {
            float d = 0.0f;
            const bool lok = (((lane >> 2) & 3) == l4);
            if (wq & 1) {
                #pragma unroll
                for (int b = 0; b < 4; ++b)
                    #pragma unroll
                    for (int r = 0; r < 4; ++r)
                        if (lok && r == (lane & 3)) d += acc[4 + b][b][r];
            } else {
                #pragma unroll
                for (int b = 0; b < 4; ++b)
                    #pragma unroll
                    for (int r = 0; r < 4; ++r)
                        if (lok && r == (lane & 3)) d += acc[b][b][r];
            }
            #pragma unroll
            for (int off = 1; off < 64; off <<= 1) d += __shfl_xor(d, off, 64);
            if (lane == 0) atomicAdd(out, -d * SCALE);
        }

        // copy stores (retire during part-write + next-tile init slack)
        #pragma unroll
        for (int i = 0; i < 12; ++i)
            *(f32x4*)(cdst + tid * 4 + i * 2048) = cbuf[i];

        if (lane < 16) {
            const size_t rowb = (size_t)s * 2048 + (size_t)qb * 256 + wq * 64 + lane;
            #pragma unroll
            for (int b = 0; b < 4; ++b)
                part[(rowb + b * 16) * 8 + kb * 2 + wk] = make_float2(q_m[b], q_s[b]);
        }
    }
    #undef READ12
    #undef MFMA32
}

// merge the 8 per-(kb,wk) partials of each row -> lse, accumulate loss
__global__ __launch_bounds__(256) void reduce_kernel(
    const float2* __restrict__ part, float* __restrict__ out)
{
    const int row = blockIdx.x * 256 + threadIdx.x;   // 392*256 = 100352 rows
    const float2* p = part + (size_t)row * 8;
    float m = -3.0e38f;
    float2 q[8];
    #pragma unroll
    for (int i = 0; i < 8; ++i) { q[i] = p[i]; m = fmaxf(m, q[i].x); }
    float ssum = 0.0f;
    #pragma unroll
    for (int i = 0; i < 8; ++i) ssum += q[i].y * __expf(q[i].x - m);
    float v = m + __logf(ssum);
    #pragma unroll
    for (int off = 1; off < 64; off <<= 1) v += __shfl_xor(v, off, 64);
    __shared__ float red[4];
    const int lane = threadIdx.x & 63, w = threadIdx.x >> 6;
    if (lane == 0) red[w] = v;
    __syncthreads();
    if (threadIdx.x == 0)
        atomicAdd(out, (red[0] + red[1] + red[2] + red[3]) * SCALE);
}

extern "C" void kernel_launch(void* const* d_in, const int* in_sizes, int n_in,
                              void* d_out, int out_size, void* d_ws, size_t ws_size,
                              hipStream_t stream)
{
    (void)in_sizes; (void)n_in; (void)out_size; (void)ws_size;
    const float* f  = (const float*)d_in[0];
    const float* x  = (const float*)d_in[1];
    const float* xp = (const float*)d_in[2];
    const float* mt = (const float*)d_in[3];
    const float* mp = (const float*)d_in[4];
    const float* ct = (const float*)d_in[5];
    const float* cp = (const float*)d_in[6];
    float* out = (float*)d_out;

    char* ws = (char*)d_ws;
    const size_t packBytes = (size_t)SDIM * NDIM * DDIM * 2;   // 51.4 MB
    __hip_bfloat16* Km = (__hip_bfloat16*)ws;
    __hip_bfloat16* Qm = (__hip_bfloat16*)(ws + packBytes);
    __hip_bfloat16* Fm = (__hip_bfloat16*)(ws + 2 * packBytes);
    float2* part = (float2*)(ws + 2 * packBytes + (size_t)NDIM * DDIM * 2);

    pack_kernel<<<NDIM, 512, 0, stream>>>(xp, mp, cp, Km);
    pack_kernel<<<NDIM, 512, 0, stream>>>(x,  mt, ct, Qm);
    fpack_kernel<<<(NDIM * DDIM + 255) / 256, 256, 0, stream>>>(f, Fm, NDIM * DDIM, out);

    loss_kernel<<<256, 512, 2 * SLOT, stream>>>(Fm, Km, Qm, xp, x, out + 1, part, out);
    reduce_kernel<<<392, 256, 0, stream>>>(part, out);
}

// Round 15
// 216.038 us; speedup vs baseline: 1.0242x; 1.0242x over previous
//
#include <hip/hip_runtime.h>
#include <hip/hip_bf16.h>

typedef __attribute__((ext_vector_type(8))) __bf16 bf16x8;
typedef __attribute__((ext_vector_type(4))) float  f32x4;

#define SDIM 49
#define NDIM 1024
#define CDIM 384
#define DDIM 512
#define DMC  64
#define SCALE (1.0f/(SDIM*NDIM))
#define SLOT4 32768  // per K-step slot: A 256x64B (16K) + B 256x64B (16K); 4 slots = 128KB
#define CHUNK 24576  // floats copied per tile: 1568*24576 == 2*1024*384*49

__device__ __forceinline__ void gload16(const void* g, void* l) {
    __builtin_amdgcn_global_load_lds((const __attribute__((address_space(1))) void*)g,
                                     (__attribute__((address_space(3))) void*)l, 16, 0, 0);
}

// ---------------------------------------------------------------------------
// pack only (copy lives in loss kernel): x [N,C,S] + m + c -> bf16 [S,N,512].
// ---------------------------------------------------------------------------
__global__ __launch_bounds__(512) void pack_kernel(
    const float* __restrict__ xloc, const float* __restrict__ mv,
    const float* __restrict__ cv,   __hip_bfloat16* __restrict__ dst)
{
    const int j = blockIdx.x;
    const int d = threadIdx.x;
    float vals[SDIM];
    if (d < CDIM) {
        const float* p = xloc + ((size_t)j * CDIM + d) * SDIM;
        #pragma unroll
        for (int s = 0; s < SDIM; ++s) vals[s] = p[s];
    } else if (d < CDIM + DMC) {
        float v = mv[j * DMC + (d - CDIM)];
        #pragma unroll
        for (int s = 0; s < SDIM; ++s) vals[s] = v;
    } else {
        float v = cv[j * DMC + (d - CDIM - DMC)];
        #pragma unroll
        for (int s = 0; s < SDIM; ++s) vals[s] = v;
    }
    #pragma unroll
    for (int s = 0; s < SDIM; ++s)
        dst[((size_t)s * NDIM + j) * DDIM + d] = __float2bfloat16(vals[s]);
}

// fpack also zero-inits the loss accumulator (replaces the memset dispatch).
__global__ void fpack_kernel(const float* __restrict__ f,
                             __hip_bfloat16* __restrict__ dst, int n,
                             float* __restrict__ out0)
{
    int i = blockIdx.x * blockDim.x + threadIdx.x;
    if (i == 0) out0[0] = 0.0f;
    if (i < n) dst[i] = __float2bfloat16(f[i]);
}

// ---------------------------------------------------------------------------
// PERSISTENT fused GEMM + partial-LSE + hidden copy, COUNTED-VMCNT 4-slot ring.
// grid = 256 blocks of 512 (8 waves = 2 wk x 4 wq); block (xcd=bid&7, jj)
// owns tiles g = 196*xcd + jj + 32k.  Tile g: s=g>>5, kb=(g>>3)&3, qb=g&7.
// Tile: 256 keys x 256 q, BK=32 (16 K-steps); wave tile 128 keys x 64 q.
// MFMA 16x16x32 bf16: acc[a=0..7][b=0..3]; C/D col=lane&15, row=(lane>>4)*4+reg.
// LDS slot (32KB): A rows [256][64B] @0, B rows [256][64B] @16K.
// Swizzle: LDS (row, o) holds G k-octet j = ((o>>4) - ((row>>1)&3)) & 3;
// read at o = ((l4 + (l15>>1)) & 3) << 4 -> lane gets octet l4 (exact);
// bank walk = 2-way aliasing (free).  Staged linear dest + per-thread source
// col jcol = (((tid&3) - ((tid>>3)&3)) & 3) << 4 (row-consistent).
// Step t: [t>=3: vmcnt(8) - slot-t loads issued at t-3, ~3 steps old, never a
// fresh drain; t=14:4, t=15:0 tail] ; s_barrier (publishes slot t, releases
// slot (t+3)&3) ; stage4(t+3) [t<=12: this tile; else next tile steps 0-2] ;
// 12 ds_read ; 32 MFMA.  Epilogue vmcnt(0) covers cbuf + pre-drains next
// tile's slots 0-2 (so steps 0-2 need no vmcnt).
// ---------------------------------------------------------------------------
__global__ __launch_bounds__(512, 2) void loss_kernel(
    const __hip_bfloat16* __restrict__ Fm,   // [N,512]
    const __hip_bfloat16* __restrict__ Km,   // [S,N,512] keys
    const __hip_bfloat16* __restrict__ Qm,   // [S,N,512] queries (pred2)
    const float* __restrict__ xp,            // copy source 1
    const float* __restrict__ xq,            // copy source 2
    float* __restrict__ outv,                // out+1 (copy dest)
    float2* __restrict__ part,               // [S*2048][8]
    float* __restrict__ out)
{
    extern __shared__ __attribute__((aligned(16))) char sm[];   // 4*SLOT4

    const int bid = blockIdx.x;
    const int xcd = bid & 7;
    const int jj  = bid >> 3;
    const int g0  = 196 * xcd;
    const int gend = g0 + 196;

    const int tid  = threadIdx.x;
    const int lane = tid & 63;
    const int w    = tid >> 6;
    const int l15  = lane & 15;
    const int l4   = lane >> 4;   // 0..3
    const int wk   = w >> 2;      // 0..1 key half
    const int wq   = w & 3;       // 0..3 q quarter

    // staging constants: round c covers rows c*128 + (tid>>2), slot (tid&3)*16
    const int srow = tid >> 2;
    const int jcol = (((tid & 3) - ((tid >> 3) & 3)) & 3) << 4;

    // read constants
    const unsigned off   = (unsigned)(((l4 + (l15 >> 1)) & 3) << 4);
    const unsigned abase = (unsigned)((wk * 128 + l15) * 64);
    const unsigned bbase = 16384u + (unsigned)((wq * 64 + l15) * 64);

    auto APtr = [&](int g) -> const char* {
        const int s = g >> 5, kb = (g >> 3) & 3;
        return (const char*)Km + ((size_t)s * NDIM + (size_t)kb * 256) * 1024;
    };
    auto BPtr = [&](int g) -> const char* {
        const int s = g >> 5, qb = g & 7;
        return (qb < 4)
            ? ((const char*)Fm + (size_t)qb * 256 * 1024)
            : ((const char*)Qm + ((size_t)s * NDIM + (size_t)(qb - 4) * 256) * 1024);
    };
    // stage one BK=32 K-step (A 2 rounds + B 2 rounds = 4 gloads/thread)
    auto stage4 = [&](const char* A, const char* B, int ko, char* slot) {
        #pragma unroll
        for (int c = 0; c < 2; ++c) {
            gload16(A + (size_t)(c * 128 + srow) * 1024 + ko + jcol,
                    slot + c * 8192 + tid * 16);
            gload16(B + (size_t)(c * 128 + srow) * 1024 + ko + jcol,
                    slot + 16384 + c * 8192 + tid * 16);
        }
    };

    f32x4 acc[8][4];
    bf16x8 afr[8], bfr[4];

    #define READ12() do {                                                     \
        _Pragma("unroll")                                                     \
        for (int a = 0; a < 8; ++a)                                           \
            afr[a] = *(const bf16x8*)(sb_ + abase + a * 1024u + off);         \
        _Pragma("unroll")                                                     \
        for (int b = 0; b < 4; ++b)                                           \
            bfr[b] = *(const bf16x8*)(sb_ + bbase + b * 1024u + off);         \
    } while (0)

    #define MFMA32() do {                                                     \
        _Pragma("unroll")                                                     \
        for (int a = 0; a < 8; ++a)                                           \
            _Pragma("unroll")                                                 \
            for (int b = 0; b < 4; ++b)                                       \
                acc[a][b] = __builtin_amdgcn_mfma_f32_16x16x32_bf16(          \
                    afr[a], bfr[b], acc[a][b], 0, 0, 0);                      \
    } while (0)

    // prologue: first tile's slots 0,1,2; drain once
    {
        const char* A0 = APtr(g0 + jj);
        const char* B0 = BPtr(g0 + jj);
        stage4(A0, B0, 0,   sm);
        stage4(A0, B0, 64,  sm + SLOT4);
        stage4(A0, B0, 128, sm + 2 * SLOT4);
        asm volatile("s_waitcnt vmcnt(0)" ::: "memory");
    }

    for (int g = g0 + jj; g < gend; g += 32) {
        const char* Ag = APtr(g);
        const char* Bg = BPtr(g);
        const bool hasNext = (g + 32) < gend;
        const char* An = hasNext ? APtr(g + 32) : Ag;
        const char* Bn = hasNext ? BPtr(g + 32) : Bg;

        #pragma unroll
        for (int a = 0; a < 8; ++a)
            #pragma unroll
            for (int b = 0; b < 4; ++b) acc[a][b] = f32x4{0.f, 0.f, 0.f, 0.f};

        #pragma unroll
        for (int t = 0; t < 16; ++t) {
            const char* sb_ = sm + (size_t)(t & 3) * SLOT4;
            char* ns_ = sm + (size_t)((t + 3) & 3) * SLOT4;

            // counted wait: slot-t loads are ~3 steps old (never a fresh drain)
            if (t == 15)      asm volatile("s_waitcnt vmcnt(0)" ::: "memory");
            else if (t == 14) asm volatile("s_waitcnt vmcnt(4)" ::: "memory");
            else if (t >= 3)  asm volatile("s_waitcnt vmcnt(8)" ::: "memory");
            __builtin_amdgcn_s_barrier();

            if (t <= 12) {
                stage4(Ag, Bg, (t + 3) * 64, ns_);
            } else if (hasNext) {
                stage4(An, Bn, (t - 13) * 64, ns_);
            }
            __builtin_amdgcn_sched_barrier(0);   // pin stage-issue first

            READ12();
            __builtin_amdgcn_s_setprio(1); MFMA32(); __builtin_amdgcn_s_setprio(0);
        }

        // ---- epilogue (12 prefetched loads for next tile stay in flight
        //      until the vmcnt(0) below; cbuf latency hides under LSE math)
        const int s  = g >> 5;
        const int kb = (g >> 3) & 3;
        const int qb = g & 7;

        const float* csrc = (g < 784) ? (xp + (size_t)g * CHUNK)
                                      : (xq + (size_t)(g - 784) * CHUNK);
        float* cdst = outv + (size_t)g * CHUNK;
        f32x4 cbuf[12];
        #pragma unroll
        for (int i = 0; i < 12; ++i)
            cbuf[i] = *(const f32x4*)(csrc + tid * 4 + i * 2048);

        float q_m[4], q_s[4];
        #pragma unroll
        for (int b = 0; b < 4; ++b) {
            float m = -3.0e38f;
            #pragma unroll
            for (int a = 0; a < 8; ++a)
                #pragma unroll
                for (int r = 0; r < 4; ++r) m = fmaxf(m, acc[a][b][r]);
            float ss = 0.0f;
            #pragma unroll
            for (int a = 0; a < 8; ++a)
                #pragma unroll
                for (int r = 0; r < 4; ++r) ss += __expf(acc[a][b][r] - m);
            #pragma unroll
            for (int off2 = 16; off2 <= 32; off2 <<= 1) {
                float mo = __shfl_xor(m, off2, 64);
                float so = __shfl_xor(ss, off2, 64);
                float nm = fmaxf(m, mo);
                ss = ss * __expf(m - nm) + so * __expf(mo - nm);
                m = nm;
            }
            q_m[b] = m; q_s[b] = ss;
        }

        // diag (reads acc)
        if (kb == (qb & 3) && (wq >> 1) == wk) {
            float d = 0.0f;
            const bool lok = (((lane >> 2) & 3) == l4);
            if (wq & 1) {
                #pragma unroll
                for (int b = 0; b < 4; ++b)
                    #pragma unroll
                    for (int r = 0; r < 4; ++r)
                        if (lok && r == (lane & 3)) d += acc[4 + b][b][r];
            } else {
                #pragma unroll
                for (int b = 0; b < 4; ++b)
                    #pragma unroll
                    for (int r = 0; r < 4; ++r)
                        if (lok && r == (lane & 3)) d += acc[b][b][r];
            }
            #pragma unroll
            for (int off2 = 1; off2 < 64; off2 <<= 1) d += __shfl_xor(d, off2, 64);
            if (lane == 0) atomicAdd(out, -d * SCALE);
        }

        // drain cbuf (+ pre-drains next tile's slots 0-2), then stores
        asm volatile("s_waitcnt vmcnt(0)" ::: "memory");
        #pragma unroll
        for (int i = 0; i < 12; ++i)
            *(f32x4*)(cdst + tid * 4 + i * 2048) = cbuf[i];

        if (lane < 16) {
            const size_t rowb = (size_t)s * 2048 + (size_t)qb * 256 + wq * 64 + lane;
            #pragma unroll
            for (int b = 0; b < 4; ++b)
                part[(rowb + b * 16) * 8 + kb * 2 + wk] = make_float2(q_m[b], q_s[b]);
        }
    }
    #undef READ12
    #undef MFMA32
}

// merge the 8 per-(kb,wk) partials of each row -> lse, accumulate loss
__global__ __launch_bounds__(256) void reduce_kernel(
    const float2* __restrict__ part, float* __restrict__ out)
{
    const int row = blockIdx.x * 256 + threadIdx.x;   // 392*256 = 100352 rows
    const float2* p = part + (size_t)row * 8;
    float m = -3.0e38f;
    float2 q[8];
    #pragma unroll
    for (int i = 0; i < 8; ++i) { q[i] = p[i]; m = fmaxf(m, q[i].x); }
    float ssum = 0.0f;
    #pragma unroll
    for (int i = 0; i < 8; ++i) ssum += q[i].y * __expf(q[i].x - m);
    float v = m + __logf(ssum);
    #pragma unroll
    for (int off = 1; off < 64; off <<= 1) v += __shfl_xor(v, off, 64);
    __shared__ float red[4];
    const int lane = threadIdx.x & 63, w = threadIdx.x >> 6;
    if (lane == 0) red[w] = v;
    __syncthreads();
    if (threadIdx.x == 0)
        atomicAdd(out, (red[0] + red[1] + red[2] + red[3]) * SCALE);
}

extern "C" void kernel_launch(void* const* d_in, const int* in_sizes, int n_in,
                              void* d_out, int out_size, void* d_ws, size_t ws_size,
                              hipStream_t stream)
{
    (void)in_sizes; (void)n_in; (void)out_size; (void)ws_size;
    const float* f  = (const float*)d_in[0];
    const float* x  = (const float*)d_in[1];
    const float* xp = (const float*)d_in[2];
    const float* mt = (const float*)d_in[3];
    const float* mp = (const float*)d_in[4];
    const float* ct = (const float*)d_in[5];
    const float* cp = (const float*)d_in[6];
    float* out = (float*)d_out;

    char* ws = (char*)d_ws;
    const size_t packBytes = (size_t)SDIM * NDIM * DDIM * 2;   // 51.4 MB
    __hip_bfloat16* Km = (__hip_bfloat16*)ws;
    __hip_bfloat16* Qm = (__hip_bfloat16*)(ws + packBytes);
    __hip_bfloat16* Fm = (__hip_bfloat16*)(ws + 2 * packBytes);
    float2* part = (float2*)(ws + 2 * packBytes + (size_t)NDIM * DDIM * 2);

    pack_kernel<<<NDIM, 512, 0, stream>>>(xp, mp, cp, Km);
    pack_kernel<<<NDIM, 512, 0, stream>>>(x,  mt, ct, Qm);
    fpack_kernel<<<(NDIM * DDIM + 255) / 256, 256, 0, stream>>>(f, Fm, NDIM * DDIM, out);

    loss_kernel<<<256, 512, 4 * SLOT4, stream>>>(Fm, Km, Qm, xp, x, out + 1, part, out);
    reduce_kernel<<<392, 256, 0, stream>>>(part, out);
}

// Round 16
// 207.496 us; speedup vs baseline: 1.0664x; 1.0412x over previous
//
#include <hip/hip_runtime.h>
#include <hip/hip_bf16.h>

typedef __attribute__((ext_vector_type(8))) __bf16 bf16x8;
typedef __attribute__((ext_vector_type(4))) float  f32x4;

#define SDIM 49
#define NDIM 1024
#define CDIM 384
#define DDIM 512
#define DMC  64
#define SCALE (1.0f/(SDIM*NDIM))
#define SLOT4 32768  // per K-step slot: A 256x64B (16K) + B 256x64B (16K); 4 slots = 128KB
#define CHUNK 24576  // floats copied per tile: 1568*24576 == 2*1024*384*49

__device__ __forceinline__ void gload16(const void* g, void* l) {
    __builtin_amdgcn_global_load_lds((const __attribute__((address_space(1))) void*)g,
                                     (__attribute__((address_space(3))) void*)l, 16, 0, 0);
}

// ---------------------------------------------------------------------------
// fused front kernel: both packs + f conversion + out[0] zero in ONE launch.
// grid 2048 x 512: bid<1024 -> pack(xp,mp,cp -> Km); else pack(x,mt,ct -> Qm).
// Every block also converts 256 elements of f (2048*256 = 1024*512 exactly).
// ---------------------------------------------------------------------------
__global__ __launch_bounds__(512) void front_kernel(
    const float* __restrict__ xp, const float* __restrict__ mp,
    const float* __restrict__ cp, __hip_bfloat16* __restrict__ Km,
    const float* __restrict__ x,  const float* __restrict__ mt,
    const float* __restrict__ ct, __hip_bfloat16* __restrict__ Qm,
    const float* __restrict__ f,  __hip_bfloat16* __restrict__ Fm,
    float* __restrict__ out0)
{
    const int bid = blockIdx.x;
    const int tid = threadIdx.x;

    // f conversion chunk (256 elems per block, threads 0..255)
    if (tid < 256) {
        const int i = bid * 256 + tid;
        Fm[i] = __float2bfloat16(f[i]);
    }
    if (bid == 0 && tid == 0) out0[0] = 0.0f;

    const bool kside = (bid < 1024);
    const int j = kside ? bid : (bid - 1024);
    const float* xloc = kside ? xp : x;
    const float* mv   = kside ? mp : mt;
    const float* cv   = kside ? cp : ct;
    __hip_bfloat16* dst = kside ? Km : Qm;

    const int d = tid;
    float vals[SDIM];
    if (d < CDIM) {
        const float* p = xloc + ((size_t)j * CDIM + d) * SDIM;
        #pragma unroll
        for (int s = 0; s < SDIM; ++s) vals[s] = p[s];
    } else if (d < CDIM + DMC) {
        float v = mv[j * DMC + (d - CDIM)];
        #pragma unroll
        for (int s = 0; s < SDIM; ++s) vals[s] = v;
    } else {
        float v = cv[j * DMC + (d - CDIM - DMC)];
        #pragma unroll
        for (int s = 0; s < SDIM; ++s) vals[s] = v;
    }
    #pragma unroll
    for (int s = 0; s < SDIM; ++s)
        dst[((size_t)s * NDIM + j) * DDIM + d] = __float2bfloat16(vals[s]);
}

// ---------------------------------------------------------------------------
// PERSISTENT fused GEMM + partial-LSE + hidden copy, COUNTED-VMCNT 4-slot ring
// (byte-identical to R15, validated 155us / MfmaUtil 29 / 0 conflicts).
// ---------------------------------------------------------------------------
__global__ __launch_bounds__(512, 2) void loss_kernel(
    const __hip_bfloat16* __restrict__ Fm,   // [N,512]
    const __hip_bfloat16* __restrict__ Km,   // [S,N,512] keys
    const __hip_bfloat16* __restrict__ Qm,   // [S,N,512] queries (pred2)
    const float* __restrict__ xp,            // copy source 1
    const float* __restrict__ xq,            // copy source 2
    float* __restrict__ outv,                // out+1 (copy dest)
    float2* __restrict__ part,               // [S*2048][8]
    float* __restrict__ out)
{
    extern __shared__ __attribute__((aligned(16))) char sm[];   // 4*SLOT4

    const int bid = blockIdx.x;
    const int xcd = bid & 7;
    const int jj  = bid >> 3;
    const int g0  = 196 * xcd;
    const int gend = g0 + 196;

    const int tid  = threadIdx.x;
    const int lane = tid & 63;
    const int w    = tid >> 6;
    const int l15  = lane & 15;
    const int l4   = lane >> 4;   // 0..3
    const int wk   = w >> 2;      // 0..1 key half
    const int wq   = w & 3;       // 0..3 q quarter

    const int srow = tid >> 2;
    const int jcol = (((tid & 3) - ((tid >> 3) & 3)) & 3) << 4;

    const unsigned off   = (unsigned)(((l4 + (l15 >> 1)) & 3) << 4);
    const unsigned abase = (unsigned)((wk * 128 + l15) * 64);
    const unsigned bbase = 16384u + (unsigned)((wq * 64 + l15) * 64);

    auto APtr = [&](int g) -> const char* {
        const int s = g >> 5, kb = (g >> 3) & 3;
        return (const char*)Km + ((size_t)s * NDIM + (size_t)kb * 256) * 1024;
    };
    auto BPtr = [&](int g) -> const char* {
        const int s = g >> 5, qb = g & 7;
        return (qb < 4)
            ? ((const char*)Fm + (size_t)qb * 256 * 1024)
            : ((const char*)Qm + ((size_t)s * NDIM + (size_t)(qb - 4) * 256) * 1024);
    };
    auto stage4 = [&](const char* A, const char* B, int ko, char* slot) {
        #pragma unroll
        for (int c = 0; c < 2; ++c) {
            gload16(A + (size_t)(c * 128 + srow) * 1024 + ko + jcol,
                    slot + c * 8192 + tid * 16);
            gload16(B + (size_t)(c * 128 + srow) * 1024 + ko + jcol,
                    slot + 16384 + c * 8192 + tid * 16);
        }
    };

    f32x4 acc[8][4];
    bf16x8 afr[8], bfr[4];

    #define READ12() do {                                                     \
        _Pragma("unroll")                                                     \
        for (int a = 0; a < 8; ++a)                                           \
            afr[a] = *(const bf16x8*)(sb_ + abase + a * 1024u + off);         \
        _Pragma("unroll")                                                     \
        for (int b = 0; b < 4; ++b)                                           \
            bfr[b] = *(const bf16x8*)(sb_ + bbase + b * 1024u + off);         \
    } while (0)

    #define MFMA32() do {                                                     \
        _Pragma("unroll")                                                     \
        for (int a = 0; a < 8; ++a)                                           \
            _Pragma("unroll")                                                 \
            for (int b = 0; b < 4; ++b)                                       \
                acc[a][b] = __builtin_amdgcn_mfma_f32_16x16x32_bf16(          \
                    afr[a], bfr[b], acc[a][b], 0, 0, 0);                      \
    } while (0)

    // prologue: first tile's slots 0,1,2; drain once
    {
        const char* A0 = APtr(g0 + jj);
        const char* B0 = BPtr(g0 + jj);
        stage4(A0, B0, 0,   sm);
        stage4(A0, B0, 64,  sm + SLOT4);
        stage4(A0, B0, 128, sm + 2 * SLOT4);
        asm volatile("s_waitcnt vmcnt(0)" ::: "memory");
    }

    for (int g = g0 + jj; g < gend; g += 32) {
        const char* Ag = APtr(g);
        const char* Bg = BPtr(g);
        const bool hasNext = (g + 32) < gend;
        const char* An = hasNext ? APtr(g + 32) : Ag;
        const char* Bn = hasNext ? BPtr(g + 32) : Bg;

        #pragma unroll
        for (int a = 0; a < 8; ++a)
            #pragma unroll
            for (int b = 0; b < 4; ++b) acc[a][b] = f32x4{0.f, 0.f, 0.f, 0.f};

        #pragma unroll
        for (int t = 0; t < 16; ++t) {
            const char* sb_ = sm + (size_t)(t & 3) * SLOT4;
            char* ns_ = sm + (size_t)((t + 3) & 3) * SLOT4;

            if (t == 15)      asm volatile("s_waitcnt vmcnt(0)" ::: "memory");
            else if (t == 14) asm volatile("s_waitcnt vmcnt(4)" ::: "memory");
            else if (t >= 3)  asm volatile("s_waitcnt vmcnt(8)" ::: "memory");
            __builtin_amdgcn_s_barrier();

            if (t <= 12) {
                stage4(Ag, Bg, (t + 3) * 64, ns_);
            } else if (hasNext) {
                stage4(An, Bn, (t - 13) * 64, ns_);
            }
            __builtin_amdgcn_sched_barrier(0);   // pin stage-issue first

            READ12();
            __builtin_amdgcn_s_setprio(1); MFMA32(); __builtin_amdgcn_s_setprio(0);
        }

        // ---- epilogue
        const int s  = g >> 5;
        const int kb = (g >> 3) & 3;
        const int qb = g & 7;

        const float* csrc = (g < 784) ? (xp + (size_t)g * CHUNK)
                                      : (xq + (size_t)(g - 784) * CHUNK);
        float* cdst = outv + (size_t)g * CHUNK;
        f32x4 cbuf[12];
        #pragma unroll
        for (int i = 0; i < 12; ++i)
            cbuf[i] = *(const f32x4*)(csrc + tid * 4 + i * 2048);

        float q_m[4], q_s[4];
        #pragma unroll
        for (int b = 0; b < 4; ++b) {
            float m = -3.0e38f;
            #pragma unroll
            for (int a = 0; a < 8; ++a)
                #pragma unroll
                for (int r = 0; r < 4; ++r) m = fmaxf(m, acc[a][b][r]);
            float ss = 0.0f;
            #pragma unroll
            for (int a = 0; a < 8; ++a)
                #pragma unroll
                for (int r = 0; r < 4; ++r) ss += __expf(acc[a][b][r] - m);
            #pragma unroll
            for (int off2 = 16; off2 <= 32; off2 <<= 1) {
                float mo = __shfl_xor(m, off2, 64);
                float so = __shfl_xor(ss, off2, 64);
                float nm = fmaxf(m, mo);
                ss = ss * __expf(m - nm) + so * __expf(mo - nm);
                m = nm;
            }
            q_m[b] = m; q_s[b] = ss;
        }

        if (kb == (qb & 3) && (wq >> 1) == wk) {
            float d = 0.0f;
            const bool lok = (((lane >> 2) & 3) == l4);
            if (wq & 1) {
                #pragma unroll
                for (int b = 0; b < 4; ++b)
                    #pragma unroll
                    for (int r = 0; r < 4; ++r)
                        if (lok && r == (lane & 3)) d += acc[4 + b][b][r];
            } else {
                #pragma unroll
                for (int b = 0; b < 4; ++b)
                    #pragma unroll
                    for (int r = 0; r < 4; ++r)
                        if (lok && r == (lane & 3)) d += acc[b][b][r];
            }
            #pragma unroll
            for (int off2 = 1; off2 < 64; off2 <<= 1) d += __shfl_xor(d, off2, 64);
            if (lane == 0) atomicAdd(out, -d * SCALE);
        }

        asm volatile("s_waitcnt vmcnt(0)" ::: "memory");
        #pragma unroll
        for (int i = 0; i < 12; ++i)
            *(f32x4*)(cdst + tid * 4 + i * 2048) = cbuf[i];

        if (lane < 16) {
            const size_t rowb = (size_t)s * 2048 + (size_t)qb * 256 + wq * 64 + lane;
            #pragma unroll
            for (int b = 0; b < 4; ++b)
                part[(rowb + b * 16) * 8 + kb * 2 + wk] = make_float2(q_m[b], q_s[b]);
        }
    }
    #undef READ12
    #undef MFMA32
}

// merge the 8 per-(kb,wk) partials of each row -> lse, accumulate loss
__global__ __launch_bounds__(256) void reduce_kernel(
    const float2* __restrict__ part, float* __restrict__ out)
{
    const int row = blockIdx.x * 256 + threadIdx.x;   // 392*256 = 100352 rows
    const float2* p = part + (size_t)row * 8;
    float m = -3.0e38f;
    float2 q[8];
    #pragma unroll
    for (int i = 0; i < 8; ++i) { q[i] = p[i]; m = fmaxf(m, q[i].x); }
    float ssum = 0.0f;
    #pragma unroll
    for (int i = 0; i < 8; ++i) ssum += q[i].y * __expf(q[i].x - m);
    float v = m + __logf(ssum);
    #pragma unroll
    for (int off = 1; off < 64; off <<= 1) v += __shfl_xor(v, off, 64);
    __shared__ float red[4];
    const int lane = threadIdx.x & 63, w = threadIdx.x >> 6;
    if (lane == 0) red[w] = v;
    __syncthreads();
    if (threadIdx.x == 0)
        atomicAdd(out, (red[0] + red[1] + red[2] + red[3]) * SCALE);
}

extern "C" void kernel_launch(void* const* d_in, const int* in_sizes, int n_in,
                              void* d_out, int out_size, void* d_ws, size_t ws_size,
                              hipStream_t stream)
{
    (void)in_sizes; (void)n_in; (void)out_size; (void)ws_size;
    const float* f  = (const float*)d_in[0];
    const float* x  = (const float*)d_in[1];
    const float* xp = (const float*)d_in[2];
    const float* mt = (const float*)d_in[3];
    const float* mp = (const float*)d_in[4];
    const float* ct = (const float*)d_in[5];
    const float* cp = (const float*)d_in[6];
    float* out = (float*)d_out;

    char* ws = (char*)d_ws;
    const size_t packBytes = (size_t)SDIM * NDIM * DDIM * 2;   // 51.4 MB
    __hip_bfloat16* Km = (__hip_bfloat16*)ws;
    __hip_bfloat16* Qm = (__hip_bfloat16*)(ws + packBytes);
    __hip_bfloat16* Fm = (__hip_bfloat16*)(ws + 2 * packBytes);
    float2* part = (float2*)(ws + 2 * packBytes + (size_t)NDIM * DDIM * 2);

    front_kernel<<<2048, 512, 0, stream>>>(xp, mp, cp, Km, x, mt, ct, Qm, f, Fm, out);
    loss_kernel<<<256, 512, 4 * SLOT4, stream>>>(Fm, Km, Qm, xp, x, out + 1, part, out);
    reduce_kernel<<<392, 256, 0, stream>>>(part, out);
}